// Round 1
// 442.656 us; speedup vs baseline: 1.0546x; 1.0546x over previous
//
#include <hip/hip_runtime.h>
#include <stdint.h>

#define NROWS 100000   // N rows of x
#define DIMD  128      // D
#define KKIDX 3        // K indices per batch row
#define NDOUT 128      // DOUT
#define KDIM  384      // K*D (nonpool reduction dim)
#define NBAT  500000   // B batch rows

typedef float  f4v  __attribute__((ext_vector_type(4)));
typedef short  s8v  __attribute__((ext_vector_type(8)));
typedef unsigned int u4v __attribute__((ext_vector_type(4)));

__device__ __forceinline__ short f2bf(float f) {
    union { float f; uint32_t u; } c; c.f = f;
    uint32_t u = c.u;
    uint32_t r = (u + 0x7FFFu + ((u >> 16) & 1u)) >> 16;   // RNE
    return (short)r;
}

// ---- prep: transpose+convert nonpool weight to bf16 wT[n][k], k contiguous ----
__global__ void k_wt(const float* __restrict__ w, unsigned short* __restrict__ wT) {
    int g = blockIdx.x * 256 + threadIdx.x;          // 0..49151
    if (g >= KDIM * NDOUT) return;
    int k = g >> 7;                                   // /128
    int n = g & 127;
    wT[n * KDIM + k] = (unsigned short)f2bf(w[g]);    // w row-major (512,128): w[k*128+n]=w[g]
}

// ---- prep: column sums of x (+ optional bf16 copy of x) ----
template<bool WRITE_BF>
__global__ void k_colsum(const float* __restrict__ x, float* __restrict__ xpool,
                         unsigned short* __restrict__ xbf) {
    __shared__ float red[256];
    int col  = threadIdx.x & 127;
    int half = threadIdx.x >> 7;
    float acc = 0.f;
    int r0 = blockIdx.x * 250;                        // 400 blocks * 250 rows = 100000
    for (int r = r0 + half; r < r0 + 250; r += 2) {
        float v = x[r * DIMD + col];
        acc += v;
        if (WRITE_BF) xbf[r * DIMD + col] = (unsigned short)f2bf(v);
    }
    red[threadIdx.x] = acc;
    __syncthreads();
    if (threadIdx.x < 128)
        atomicAdd(&xpool[col], red[threadIdx.x] + red[threadIdx.x + 128]);
}

// ---- prep: pool_out[j] = sum_d xpool[d] * w[(384+d)*128 + j]  (fp32 exact) ----
__global__ void k_pool(const float* __restrict__ xpool, const float* __restrict__ w,
                       float* __restrict__ pool_out) {
    int j = threadIdx.x;   // 128 threads
    float acc = 0.f;
    for (int d = 0; d < DIMD; ++d)
        acc += xpool[d] * w[(KDIM + d) * NDOUT + j];
    pool_out[j] = acc;
}

// ---- main GEMM: block = 512 thr (8 waves); wave tile = 32 rows x 128 cols ----
// acc[2][8] = 64 VGPR -> target <=128 VGPR total -> 4 waves/SIMD (2 blocks/CU).
#define LSTR 200   // shorts per LDS weight row: 192 + 8 pad = 400 B (16B-aligned, odd dw/4)

template<bool XBF>
__global__ __launch_bounds__(512, 4)
void k_main(const float* __restrict__ x, const unsigned short* __restrict__ xbf,
            const int* __restrict__ idx, const unsigned short* __restrict__ wT,
            const float* __restrict__ pool, float* __restrict__ out) {
    __shared__ short wlds[128 * LSTR];                // 51200 B, holds half the K range
    const int tid  = threadIdx.x;
    const int wave = tid >> 6;
    const int lane = tid & 63;
    const int quad = lane >> 4;
    const int l16  = lane & 15;

    const int rowb = blockIdx.x * 256 + wave * 32;

    // per-lane gather bases: row m = l16 of each of 2 m-tiles, 3 source rows each
    int goff[2][KKIDX];
    #pragma unroll
    for (int mt = 0; mt < 2; ++mt) {
        int r = rowb + mt * 16 + l16;
        if (r >= NBAT) r = NBAT - 1;                  // clamp (stores are guarded)
        #pragma unroll
        for (int s = 0; s < KKIDX; ++s)
            goff[mt][s] = idx[r * 3 + s] * DIMD;
    }

    f4v acc[2][8];
    #pragma unroll
    for (int mt = 0; mt < 2; ++mt)
        #pragma unroll
        for (int nt = 0; nt < 8; ++nt) {
            f4v z = {0.f, 0.f, 0.f, 0.f};
            acc[mt][nt] = z;
        }

    const int sn   = tid >> 2;   // 0..127: weight row this thread stages
    const int sseg = tid & 3;    // 0..3: 48-element segment

    // prefetch x fragments for kstep 0 (srci=0, colb=quad*8)
    s8v aC[2];
    #pragma unroll
    for (int mt = 0; mt < 2; ++mt) {
        if (XBF) {
            aC[mt] = *(const s8v*)(xbf + goff[mt][0] + quad * 8);
        } else {
            const float* ap = x + goff[mt][0] + quad * 8;
            f4v v0 = *(const f4v*)ap;
            f4v v1 = *(const f4v*)(ap + 4);
            s8v a;
            a[0] = f2bf(v0[0]); a[1] = f2bf(v0[1]);
            a[2] = f2bf(v0[2]); a[3] = f2bf(v0[3]);
            a[4] = f2bf(v1[0]); a[5] = f2bf(v1[1]);
            a[6] = f2bf(v1[2]); a[7] = f2bf(v1[3]);
            aC[mt] = a;
        }
    }

    #pragma unroll
    for (int p = 0; p < 2; ++p) {
        __syncthreads();
        // stage wT k-range [p*192, p*192+192) into LDS, 16B chunks
        #pragma unroll
        for (int j = 0; j < 6; ++j) {
            int k = sseg * 48 + j * 8;
            *(u4v*)(&wlds[sn * LSTR + k]) = *(const u4v*)(wT + sn * KDIM + p * 192 + k);
        }
        __syncthreads();

        #pragma unroll
        for (int ks = 0; ks < 6; ++ks) {
            const int kstep = p * 6 + ks;             // 0..11 global k-step (32 wide)

            // prefetch next kstep's x fragments (global, independent of LDS barriers)
            s8v aN[2];
            if (kstep < 11) {
                const int kn   = kstep + 1;
                const int srci = kn >> 2;             // which of the 3 gathered x rows
                const int colb = (kn & 3) * 32 + quad * 8;
                #pragma unroll
                for (int mt = 0; mt < 2; ++mt) {
                    if (XBF) {
                        aN[mt] = *(const s8v*)(xbf + goff[mt][srci] + colb);
                    } else {
                        const float* ap = x + goff[mt][srci] + colb;
                        f4v v0 = *(const f4v*)ap;
                        f4v v1 = *(const f4v*)(ap + 4);
                        s8v a;
                        a[0] = f2bf(v0[0]); a[1] = f2bf(v0[1]);
                        a[2] = f2bf(v0[2]); a[3] = f2bf(v0[3]);
                        a[4] = f2bf(v1[0]); a[5] = f2bf(v1[1]);
                        a[6] = f2bf(v1[2]); a[7] = f2bf(v1[3]);
                        aN[mt] = a;
                    }
                }
            }

            const int krow = ks * 32 + quad * 8;      // local k within phase
            // swapped operands: mfma(W-frag as A, X-frag as B) -> acc holds
            // 4 consecutive OUTPUT COLS per register quad (row = l16)
            #pragma unroll
            for (int h = 0; h < 2; ++h) {             // two nt-groups of 4: caps VGPRs
                s8v bF[4];
                #pragma unroll
                for (int q = 0; q < 4; ++q)
                    bF[q] = *(const s8v*)(&wlds[((h * 4 + q) * 16 + l16) * LSTR + krow]);
                #pragma unroll
                for (int mt = 0; mt < 2; ++mt)
                    #pragma unroll
                    for (int q = 0; q < 4; ++q)
                        acc[mt][h * 4 + q] = __builtin_amdgcn_mfma_f32_16x16x32_bf16(
                            bF[q], aC[mt], acc[mt][h * 4 + q], 0, 0, 0);
            }

            if (kstep < 11) { aC[0] = aN[0]; aC[1] = aN[1]; }
        }
    }

    // epilogue: acc[mt][nt][i] = out[rowb+mt*16+l16][nt*16+quad*4+i] -> float4 stores
    #pragma unroll
    for (int nt = 0; nt < 8; ++nt) {
        f4v pv = *(const f4v*)(pool + nt * 16 + quad * 4);
        #pragma unroll
        for (int mt = 0; mt < 2; ++mt) {
            int r = rowb + mt * 16 + l16;
            if (r < NBAT) {
                f4v v = acc[mt][nt] + pv;
                __builtin_nontemporal_store(v,
                    (f4v*)(out + (size_t)r * NDOUT + nt * 16 + quad * 4));
            }
        }
    }
}

extern "C" void kernel_launch(void* const* d_in, const int* in_sizes, int n_in,
                              void* d_out, int out_size, void* d_ws, size_t ws_size,
                              hipStream_t stream) {
    const float* x   = (const float*)d_in[0];
    const int*   idx = (const int*)d_in[1];
    const float* w   = (const float*)d_in[2];
    float*       out = (float*)d_out;

    char* ws = (char*)d_ws;
    float* xpool           = (float*)ws;                       // 512 B
    float* pool_out        = (float*)(ws + 512);               // 512 B
    unsigned short* wT     = (unsigned short*)(ws + 1024);     // 98304 B
    unsigned short* xbf    = (unsigned short*)(ws + 99328);    // optional 25.6 MB
    const size_t NEED_BIG  = 99328 + (size_t)NROWS * DIMD * 2;
    const bool big = ws_size >= NEED_BIG;

    hipMemsetAsync(xpool, 0, 512, stream);
    if (big) k_colsum<true ><<<400, 256, 0, stream>>>(x, xpool, xbf);
    else     k_colsum<false><<<400, 256, 0, stream>>>(x, xpool, xbf);
    k_wt  <<<192, 256, 0, stream>>>(w, wT);
    k_pool<<<1, 128, 0, stream>>>(xpool, w, pool_out);

    const int grid = (NBAT + 255) / 256;   // 1954
    if (big) k_main<true ><<<grid, 512, 0, stream>>>(x, xbf, idx, wT, pool_out, out);
    else     k_main<false><<<grid, 512, 0, stream>>>(x, xbf, idx, wT, pool_out, out);
}